// Round 6
// baseline (215.408 us; speedup 1.0000x reference)
//
#include <hip/hip_runtime.h>
#include <hip/hip_bf16.h>

#define S_LEN 4096
#define HDIM  64
#define NH    8

// ws layout (ushort element offsets), big-ws path:
//   XFRAG: 3 * 4194304   bf16 X (q,k,v inputs) in frag-tile layout
//   WFRAG: 3 * 262144    bf16 W in frag-tile layout
//   QKV:   Q(4194304) K(4194304) Vt(4194304), per-bh 262144, frag-tile layouts
#define XFRAG_OFF 0
#define WFRAG_OFF 12582912
#define QKV_OFF   13369344
#define WS_NEED_BYTES ((size_t)(13369344 + 12582912) * 2)      // 51,904,512

typedef short s16x8 __attribute__((ext_vector_type(8)));
typedef float f32x16 __attribute__((ext_vector_type(16)));
typedef unsigned short u16x4 __attribute__((ext_vector_type(4)));
typedef int i32x2 __attribute__((ext_vector_type(2)));

union FragU {
    s16x8 v;
    unsigned int u[4];
    unsigned short h[8];
};

static __device__ __forceinline__ unsigned int pack2_bf16(float a, float b) {
    __hip_bfloat162 h2 = __float22bfloat162_rn(float2{a, b});
    union { __hip_bfloat162 h; unsigned int u; } cv;
    cv.h = h2;
    return cv.u;
}

static __device__ __forceinline__ unsigned short to_bf16(float a) {
    __hip_bfloat16 h = __float2bfloat16(a);
    union { __hip_bfloat16 h; unsigned short u; } cv;
    cv.h = h;
    return cv.u;
}

// log2(e)/64 : folds the 1/hd score scale and exp->exp2 into Q
#define Q_PRESCALE 0.022542110f
// log2(1e8)/128
#define FREQ_L2 0.20762050593046f

// ---------------------------------------------------------------------------
// fp32 -> bf16 convert + reorder into MFMA frag-tile layout, LDS-staged
// (dense global reads AND dense global writes). Unchanged.
// grid (272,1,3), block 256.
// ---------------------------------------------------------------------------
__global__ __launch_bounds__(256) void conv_frag3(
    const float* __restrict__ qx, const float* __restrict__ kx,
    const float* __restrict__ vx,
    const float* __restrict__ Wq, const float* __restrict__ Wk,
    const float* __restrict__ Wv,
    unsigned short* __restrict__ xdst, unsigned short* __restrict__ wdst)
{
    __shared__ __align__(16) unsigned short slds[16640];   // 32*520 + pad

    const int z  = blockIdx.z;
    const int bx = blockIdx.x;
    const int tid  = threadIdx.x;
    const int w    = tid >> 6;
    const int lane = tid & 63;

    const float* src;
    unsigned short* dst;
    if (bx < 256) {
        src = ((z == 0) ? qx : ((z == 1) ? kx : vx)) + (size_t)bx * 32 * 512;
        dst = xdst + (size_t)z * 4194304 + (size_t)bx * 16384;
    } else {
        const int s = bx - 256;
        src = ((z == 0) ? Wq : ((z == 1) ? Wk : Wv)) + (size_t)s * 32 * 512;
        dst = wdst + (size_t)z * 262144 + (size_t)s * 16384;
    }

    #pragma unroll
    for (int i = 0; i < 8; ++i) {
        const int r = w * 8 + i;
        const float4* p = (const float4*)(src + (size_t)r * 512 + lane * 8);
        float4 x0 = p[0], x1 = p[1];
        FragU f;
        f.u[0] = pack2_bf16(x0.x, x0.y);
        f.u[1] = pack2_bf16(x0.z, x0.w);
        f.u[2] = pack2_bf16(x1.x, x1.y);
        f.u[3] = pack2_bf16(x1.z, x1.w);
        *(s16x8*)(slds + (lane >> 1) * 520 + ((lane & 1) * 32 + r) * 8) = f.v;
    }
    __syncthreads();

    #pragma unroll
    for (int i = 0; i < 8; ++i) {
        const int kc = w * 8 + i;
        s16x8 v = *(const s16x8*)(slds + kc * 520 + lane * 8);
        *(s16x8*)(dst + kc * 512 + lane * 8) = v;
    }
}

// ---------------------------------------------------------------------------
// Shared epilogue for the QKV GEMM (unchanged, verified r4-r7).
// ---------------------------------------------------------------------------
static __device__ __forceinline__ void qkv_epilogue(
    int z, const f32x16 acc[2][2], int m0, int n0, int c31, int hi,
    const float* __restrict__ bias, unsigned short* __restrict__ dst_base)
{
    if (z < 2) {
        unsigned short* dst = dst_base + (size_t)z * 4194304;
        #pragma unroll
        for (int nt = 0; nt < 2; ++nt) {
            const int s_g = n0 + nt * 32 + c31;       // global token
            const int b   = s_g >> 12;
            const int s   = s_g & 4095;
            const float pos0 = (float)(s >> 6);
            const float pos1 = (float)(s & 63);
            #pragma unroll
            for (int mt = 0; mt < 2; ++mt) {
                #pragma unroll
                for (int g = 0; g < 4; ++g) {
                    const int o_b = m0 + mt * 32 + 8 * g + 4 * hi;   // 4-aligned channel quad
                    const float4 bb = *(const float4*)(bias + o_b);
                    float v0 = acc[mt][nt][4 * g + 0] + bb.x;
                    float v1 = acc[mt][nt][4 * g + 1] + bb.y;
                    float v2 = acc[mt][nt][4 * g + 2] + bb.z;
                    float v3 = acc[mt][nt][4 * g + 3] + bb.w;
                    const float fr0 = exp2f(-(float)(o_b >> 2) * FREQ_L2);
                    float sn0, cs0, sn1, cs1;
                    __sincosf(pos0 * fr0, &sn0, &cs0);
                    __sincosf(pos1 * fr0, &sn1, &cs1);
                    float r0 = v0 * cs0 - v1 * sn0;
                    float r1 = v0 * sn0 + v1 * cs0;
                    float r2 = v2 * cs1 - v3 * sn1;
                    float r3 = v2 * sn1 + v3 * cs1;
                    if (z == 0) { r0 *= Q_PRESCALE; r1 *= Q_PRESCALE; r2 *= Q_PRESCALE; r3 *= Q_PRESCALE; }
                    const int bh = b * NH + (o_b >> 6);
                    const int k6 = o_b & 63;
                    u16x4 pk;
                    pk.x = to_bf16(r0); pk.y = to_bf16(r1);
                    pk.z = to_bf16(r2); pk.w = to_bf16(r3);
                    const size_t off = (size_t)bh * 262144 + (s >> 5) * 2048
                                     + (k6 >> 4) * 512 + (((k6 >> 3) & 1) * 32 + (s & 31)) * 8 + (k6 & 7);
                    *(u16x4*)(dst + off) = pk;
                }
            }
        }
    } else {
        unsigned short* dst = dst_base + 8388608;
        #pragma unroll
        for (int nt = 0; nt < 2; ++nt) {
            const int o  = n0 + nt * 32 + c31;        // channel (per lane)
            const float bv_ = bias[o];
            const int d = o & 63, hh = o >> 6;
            #pragma unroll
            for (int mt = 0; mt < 2; ++mt) {
                #pragma unroll
                for (int g = 0; g < 4; ++g) {
                    const int s_b = m0 + mt * 32 + 8 * g + 4 * hi;  // 4-aligned token quad
                    const int b = s_b >> 12;
                    const int s = s_b & 4095;
                    const int bh = b * NH + hh;
                    u16x4 pk;
                    pk.x = to_bf16(acc[mt][nt][4 * g + 0] + bv_);
                    pk.y = to_bf16(acc[mt][nt][4 * g + 1] + bv_);
                    pk.z = to_bf16(acc[mt][nt][4 * g + 2] + bv_);
                    pk.w = to_bf16(acc[mt][nt][4 * g + 3] + bv_);
                    const size_t off = (size_t)bh * 262144 + (s >> 5) * 2048 + (d >> 5) * 1024
                                     + ((s >> 4) & 1) * 512 + (((s >> 3) & 1) * 32 + (d & 31)) * 8 + (s & 7);
                    *(u16x4*)(dst + off) = pk;
                }
            }
        }
    }
}

// ---------------------------------------------------------------------------
// Kernel 1: QKV projection GEMM from frag-tile bf16 operands.
//   NEW this round: explicit register double-buffer on the K-loop — load
//   kc+1's 4 operand fragments BEFORE kc's MFMAs (same pattern as flash's
//   ka prefetch, r5-verified). Previously each kc's MFMAs waited on loads
//   issued immediately prior (~200-600cy L2/L3 latency, only ~64cy of MFMA
//   to hide it) -> latency-bound. Grid unchanged: y-sibling blocks (share
//   X rows) are stride-64 in dispatch order = same XCD already.
// grid (64, 4, 3), block 256.
// ---------------------------------------------------------------------------
__global__ __launch_bounds__(256) void qkv_gemm_rope(
    const unsigned short* __restrict__ xf, const unsigned short* __restrict__ wf,
    const float* __restrict__ bq, const float* __restrict__ bk,
    const float* __restrict__ bv, unsigned short* __restrict__ dst_base)
{
    const int z = blockIdx.z;
    const float* bias = (z == 0) ? bq : ((z == 1) ? bk : bv);
    const unsigned short* X = xf + (size_t)z * 4194304;
    const unsigned short* W = wf + (size_t)z * 262144;

    const int tid  = threadIdx.x;
    const int wv   = tid >> 6;
    const int lane = tid & 63;
    const int c31  = lane & 31;
    const int hi   = lane >> 5;
    const int wm   = wv >> 1, wn = wv & 1;

    int m0, n0;
    const unsigned short *A, *B;
    if (z < 2) {  // transposed: A = W (channels), B = X (tokens)
        m0 = blockIdx.y * 128 + wm * 64;
        n0 = blockIdx.x * 128 + wn * 64;
        A = W; B = X;
    } else {      // normal: A = X (tokens), B = W (channels)
        m0 = blockIdx.x * 128 + wm * 64;
        n0 = blockIdx.y * 128 + wn * 64;
        A = X; B = W;
    }

    const unsigned short* ap0 = A + (size_t)(m0 >> 5) * 16384 + lane * 8;
    const unsigned short* ap1 = ap0 + 16384;
    const unsigned short* bp0 = B + (size_t)(n0 >> 5) * 16384 + lane * 8;
    const unsigned short* bp1 = bp0 + 16384;

    f32x16 acc[2][2];
    #pragma unroll
    for (int a = 0; a < 2; ++a)
    #pragma unroll
    for (int b = 0; b < 2; ++b)
    #pragma unroll
    for (int r = 0; r < 16; ++r) acc[a][b][r] = 0.f;

    // register double-buffer: cur (c) / next (n)
    s16x8 ac0 = *(const s16x8*)(ap0);
    s16x8 ac1 = *(const s16x8*)(ap1);
    s16x8 bc0 = *(const s16x8*)(bp0);
    s16x8 bc1 = *(const s16x8*)(bp1);

    #pragma unroll
    for (int kc = 0; kc < 32; kc += 2) {
        const int ko1 = (kc + 1) * 512;
        s16x8 an0 = *(const s16x8*)(ap0 + ko1);
        s16x8 an1 = *(const s16x8*)(ap1 + ko1);
        s16x8 bn0 = *(const s16x8*)(bp0 + ko1);
        s16x8 bn1 = *(const s16x8*)(bp1 + ko1);
        acc[0][0] = __builtin_amdgcn_mfma_f32_32x32x16_bf16(ac0, bc0, acc[0][0], 0, 0, 0);
        acc[0][1] = __builtin_amdgcn_mfma_f32_32x32x16_bf16(ac0, bc1, acc[0][1], 0, 0, 0);
        acc[1][0] = __builtin_amdgcn_mfma_f32_32x32x16_bf16(ac1, bc0, acc[1][0], 0, 0, 0);
        acc[1][1] = __builtin_amdgcn_mfma_f32_32x32x16_bf16(ac1, bc1, acc[1][1], 0, 0, 0);
        if (kc + 2 < 32) {
            const int ko2 = (kc + 2) * 512;
            ac0 = *(const s16x8*)(ap0 + ko2);
            ac1 = *(const s16x8*)(ap1 + ko2);
            bc0 = *(const s16x8*)(bp0 + ko2);
            bc1 = *(const s16x8*)(bp1 + ko2);
        }
        acc[0][0] = __builtin_amdgcn_mfma_f32_32x32x16_bf16(an0, bn0, acc[0][0], 0, 0, 0);
        acc[0][1] = __builtin_amdgcn_mfma_f32_32x32x16_bf16(an0, bn1, acc[0][1], 0, 0, 0);
        acc[1][0] = __builtin_amdgcn_mfma_f32_32x32x16_bf16(an1, bn0, acc[1][0], 0, 0, 0);
        acc[1][1] = __builtin_amdgcn_mfma_f32_32x32x16_bf16(an1, bn1, acc[1][1], 0, 0, 0);
    }

    qkv_epilogue(z, acc, m0, n0, c31, hi, bias, dst_base);
}

// ---------------------------------------------------------------------------
// Kernel 1 fallback (fp32 inputs directly; used only if ws too small).
// ---------------------------------------------------------------------------
__global__ __launch_bounds__(256) void qkv_rope_f32(
    const float* __restrict__ q_in, const float* __restrict__ k_in,
    const float* __restrict__ v_in,
    const float* __restrict__ Wq, const float* __restrict__ bq,
    const float* __restrict__ Wk, const float* __restrict__ bk,
    const float* __restrict__ Wv, const float* __restrict__ bv,
    unsigned short* __restrict__ dst_base)
{
    const int z = blockIdx.z;
    const float* Xr = (z == 0) ? q_in : ((z == 1) ? k_in : v_in);
    const float* Wr = (z == 0) ? Wq   : ((z == 1) ? Wk   : Wv);
    const float* bias = (z == 0) ? bq : ((z == 1) ? bk : bv);

    const int tid  = threadIdx.x;
    const int wv   = tid >> 6;
    const int lane = tid & 63;
    const int c31  = lane & 31;
    const int hi   = lane >> 5;
    const int wm   = wv >> 1, wn = wv & 1;

    int m0, n0;
    const float *A, *B;
    if (z < 2) { m0 = blockIdx.y * 128 + wm * 64; n0 = blockIdx.x * 128 + wn * 64; A = Wr; B = Xr; }
    else       { m0 = blockIdx.x * 128 + wm * 64; n0 = blockIdx.y * 128 + wn * 64; A = Xr; B = Wr; }

    f32x16 acc[2][2];
    #pragma unroll
    for (int a = 0; a < 2; ++a)
    #pragma unroll
    for (int b = 0; b < 2; ++b)
    #pragma unroll
    for (int r = 0; r < 16; ++r) acc[a][b][r] = 0.f;

    for (int kc = 0; kc < 32; ++kc) {
        const int kofs = kc * 16 + hi * 8;
        FragU a_f[2], b_f[2];
        #pragma unroll
        for (int mt = 0; mt < 2; ++mt) {
            const float4* p = (const float4*)(A + (size_t)(m0 + mt * 32 + c31) * 512 + kofs);
            float4 x0 = p[0], x1 = p[1];
            a_f[mt].u[0] = pack2_bf16(x0.x, x0.y);
            a_f[mt].u[1] = pack2_bf16(x0.z, x0.w);
            a_f[mt].u[2] = pack2_bf16(x1.x, x1.y);
            a_f[mt].u[3] = pack2_bf16(x1.z, x1.w);
        }
        #pragma unroll
        for (int nt = 0; nt < 2; ++nt) {
            const float4* p = (const float4*)(B + (size_t)(n0 + nt * 32 + c31) * 512 + kofs);
            float4 x0 = p[0], x1 = p[1];
            b_f[nt].u[0] = pack2_bf16(x0.x, x0.y);
            b_f[nt].u[1] = pack2_bf16(x0.z, x0.w);
            b_f[nt].u[2] = pack2_bf16(x1.x, x1.y);
            b_f[nt].u[3] = pack2_bf16(x1.z, x1.w);
        }
        #pragma unroll
        for (int mt = 0; mt < 2; ++mt)
        #pragma unroll
        for (int nt = 0; nt < 2; ++nt)
            acc[mt][nt] = __builtin_amdgcn_mfma_f32_32x32x16_bf16(
                a_f[mt].v, b_f[nt].v, acc[mt][nt], 0, 0, 0);
    }

    qkv_epilogue(z, acc, m0, n0, c31, hi, bias, dst_base);
}

// ---------------------------------------------------------------------------
// P-fragment build from 4 packed-bf16 words via v_permlane32_swap_b32.
// (r3-verified, flash 180->159us). One instr yields two fragment words.
// ---------------------------------------------------------------------------
static __device__ __forceinline__ s16x8 build_pfrag(
    unsigned int a0, unsigned int a1, unsigned int a2, unsigned int a3)
{
    i32x2 r02 = __builtin_amdgcn_permlane32_swap((int)a0, (int)a2, false, false);
    i32x2 r13 = __builtin_amdgcn_permlane32_swap((int)a1, (int)a3, false, false);
    FragU pb;
    pb.u[0] = (unsigned int)r02.x;
    pb.u[1] = (unsigned int)r13.x;
    pb.u[2] = (unsigned int)r02.y;
    pb.u[3] = (unsigned int)r13.y;
    return pb.v;
}

// ---------------------------------------------------------------------------
// Kernel 2: flash attention (S^T trick) — r5 structure (85.4us verified:
// Q reg-hoisted, launch_bounds(256,2), permlane pfrag, V single-buffer).
//   NEW this round: zero-C trick. MFMA's C (src2) and D (vdst) are separate
//   operand fields, so the first MFMA of each S^T chain reads a persistent
//   zero_c register set as C instead of zeroing st0/st1 (32 v_movs) every
//   iteration. +16 regs (budget: 2 waves/SIMD = 256 unified, ~200 used),
//   -32 VALU cy/iter (VALUBusy was 53% — the busier pipe).
// grid (1024), block 256.
// ---------------------------------------------------------------------------
__global__ __launch_bounds__(256, 2) void flash_attn_st(
    const unsigned short* __restrict__ qkv, float* __restrict__ out)
{
    __shared__ __align__(16) unsigned char smem[32768 + 1024];
    unsigned short* sQ = (unsigned short*)smem;            // 8KB, prologue only
    float* sOb = (float*)smem;                             // 32KB, epilogue only
    float* sL  = (float*)(smem + 32768);                   // 1KB, disjoint from sQ

    const int tid  = threadIdx.x;
    const int wv   = tid >> 6;       // kv-split index 0..3
    const int lane = tid & 63;
    const int c31  = lane & 31;
    const int hi   = lane >> 5;
    const int id   = blockIdx.x;
    const int bh   = id & 15;        // id % 8 == bh % 8  -> XCD-local K/V
    const int q0   = (id >> 4) * 64;

    const unsigned short* Qb  = qkv + (size_t)bh * 262144;
    const unsigned short* Kb  = qkv + (size_t)4194304 + (size_t)bh * 262144;
    const unsigned short* Vtb = qkv + (size_t)8388608 + (size_t)bh * 262144;

    // cooperative Q -> LDS (8 chunks x 64 entries x 16B)
    #pragma unroll
    for (int i = 0; i < 2; ++i) {
        const int idx   = tid + i * 256;
        const int chunk = idx >> 6;
        const int ln    = idx & 63;
        *(s16x8*)(sQ + chunk * 512 + ln * 8) =
            *(const s16x8*)(Qb + (size_t)((q0 >> 5) + (chunk >> 2)) * 2048 + (chunk & 3) * 512 + ln * 8);
    }
    __syncthreads();

    // Q fragments: LDS -> registers ONCE (r5-verified win).
    s16x8 qf0[4], qf1[4];
    #pragma unroll
    for (int kc = 0; kc < 4; ++kc) {
        qf0[kc] = *(const s16x8*)(sQ + kc * 512 + lane * 8);
        qf1[kc] = *(const s16x8*)(sQ + 2048 + kc * 512 + lane * 8);
    }

    f32x16 o_acc[2][2];                   // [d-tile][q-tile], O^T layout
    #pragma unroll
    for (int a = 0; a < 2; ++a)
    #pragma unroll
    for (int b = 0; b < 2; ++b)
    #pragma unroll
    for (int r = 0; r < 16; ++r) o_acc[a][b][r] = 0.f;
    float l_acc[2] = {0.f, 0.f};

    // persistent zero accumulator seed (read-only C operand for chain heads)
    f32x16 zero_c;
    #pragma unroll
    for (int r = 0; r < 16; ++r) zero_c[r] = 0.f;

    const unsigned short* kp = Kb  + (size_t)wv * 2048 + lane * 8;   // += 8192/iter
    const unsigned short* vp = Vtb + (size_t)wv * 2048 + lane * 8;   // += 8192/iter

    // preload K A-frags for iter 0
    s16x8 ka[4];
    #pragma unroll
    for (int kc = 0; kc < 4; ++kc)
        ka[kc] = *(const s16x8*)(kp + kc * 512);

    for (int it = 0; it < 32; ++it) {
        // ---- issue V^T A-frag loads now; consumed at PV ----
        s16x8 va[2][2];
        va[0][0] = *(const s16x8*)(vp);
        va[0][1] = *(const s16x8*)(vp + 512);
        va[1][0] = *(const s16x8*)(vp + 1024);
        va[1][1] = *(const s16x8*)(vp + 1536);
        vp += 8192;

        // ---- S^T(q0) then S^T(q1): chains seeded from zero_c (no movs) ----
        f32x16 st0, st1;
        __builtin_amdgcn_s_setprio(1);
        st0 = __builtin_amdgcn_mfma_f32_32x32x16_bf16(ka[0], qf0[0], zero_c, 0, 0, 0);
        #pragma unroll
        for (int kc = 1; kc < 4; ++kc)
            st0 = __builtin_amdgcn_mfma_f32_32x32x16_bf16(ka[kc], qf0[kc], st0, 0, 0, 0);
        st1 = __builtin_amdgcn_mfma_f32_32x32x16_bf16(ka[0], qf1[0], zero_c, 0, 0, 0);
        #pragma unroll
        for (int kc = 1; kc < 4; ++kc)
            st1 = __builtin_amdgcn_mfma_f32_32x32x16_bf16(ka[kc], qf1[kc], st1, 0, 0, 0);
        __builtin_amdgcn_s_setprio(0);

        // ---- prefetch next iter's K into the SAME ka regs (after last use) ----
        kp += 8192;
        if (it < 31) {
            #pragma unroll
            for (int kc = 0; kc < 4; ++kc)
                ka[kc] = *(const s16x8*)(kp + kc * 512);
        }

        // ---- q0: exp + pack + l (VALU, overlaps q1's queued S^T MFMAs) ----
        unsigned int up0[8];
        {
            float ls0 = 0.f, ls1 = 0.f;
            #pragma unroll
            for (int qq = 0; qq < 8; ++qq) {
                float p0 = __builtin_amdgcn_exp2f(st0[2 * qq]);
                float p1 = __builtin_amdgcn_exp2f(st0[2 * qq + 1]);
                ls0 += p0; ls1 += p1;
                up0[qq] = pack2_bf16(p0, p1);
            }
            l_acc[0] += ls0 + ls1;
        }

        // ---- PV(q0): queued on matrix pipe before q1's exp runs on VALU ----
        #pragma unroll
        for (int k2 = 0; k2 < 2; ++k2) {
            s16x8 pfrag = build_pfrag(up0[4 * k2 + 0], up0[4 * k2 + 1],
                                      up0[4 * k2 + 2], up0[4 * k2 + 3]);
            __builtin_amdgcn_s_setprio(1);
            #pragma unroll
            for (int dt = 0; dt < 2; ++dt)
                o_acc[dt][0] = __builtin_amdgcn_mfma_f32_32x32x16_bf16(
                    va[dt][k2], pfrag, o_acc[dt][0], 0, 0, 0);
            __builtin_amdgcn_s_setprio(0);
        }

        // ---- q1: exp + pack + l (VALU, overlaps PV(q0) MFMAs) ----
        unsigned int up1[8];
        {
            float ls0 = 0.f, ls1 = 0.f;
            #pragma unroll
            for (int qq = 0; qq < 8; ++qq) {
                float p0 = __builtin_amdgcn_exp2f(st1[2 * qq]);
                float p1 = __builtin_amdgcn_exp2f(st1[2 * qq + 1]);
                ls0 += p0; ls1 += p1;
                up1[qq] = pack2_bf16(p0, p1);
            }
            l_acc[1] += ls0 + ls1;
        }

        // ---- PV(q1) ----
        #pragma unroll
        for (int k2 = 0; k2 < 2; ++k2) {
            s16x8 pfrag = build_pfrag(up1[4 * k2 + 0], up1[4 * k2 + 1],
                                      up1[4 * k2 + 2], up1[4 * k2 + 3]);
            __builtin_amdgcn_s_setprio(1);
            #pragma unroll
            for (int dt = 0; dt < 2; ++dt)
                o_acc[dt][1] = __builtin_amdgcn_mfma_f32_32x32x16_bf16(
                    va[dt][k2], pfrag, o_acc[dt][1], 0, 0, 0);
            __builtin_amdgcn_s_setprio(0);
        }
    }

    // ---- merge partials across the 4 kv-split waves (r4-verified) ----
    // sL is disjoint from sQ; sQ itself is dead after the prologue reads.
    {
        float l0 = l_acc[0] + __shfl_xor(l_acc[0], 32);
        float l1 = l_acc[1] + __shfl_xor(l_acc[1], 32);
        if (lane < 32) {
            sL[(wv * 2 + 0) * 32 + lane] = l0;
            sL[(wv * 2 + 1) * 32 + lane] = l1;
        }
    }
    __syncthreads();
    // All waves past the loop: the sOb region (aliasing sQ) is free to use.

    if (wv == 1 || wv == 2) {
        float* buf = sOb + (wv - 1) * 4096;
        #pragma unroll
        for (int dt = 0; dt < 2; ++dt)
        #pragma unroll
        for (int qt = 0; qt < 2; ++qt)
        #pragma unroll
        for (int r = 0; r < 16; ++r) {
            const int d = dt * 32 + (r & 3) + 8 * (r >> 2) + 4 * hi;
            buf[d * 64 + qt * 32 + c31] = o_acc[dt][qt][r];
        }
    }
    __syncthreads();
    if (wv == 0 || wv == 3) {
        const float* buf = sOb + ((wv == 0) ? 0 : 4096);
        #pragma unroll
        for (int dt = 0; dt < 2; ++dt)
        #pragma unroll
        for (int qt = 0; qt < 2; ++qt)
        #pragma unroll
        for (int r = 0; r < 16; ++r) {
            const int d = dt * 32 + (r & 3) + 8 * (r >> 2) + 4 * hi;
            o_acc[dt][qt][r] += buf[d * 64 + qt * 32 + c31];
        }
    }
    __syncthreads();
    if (wv == 3) {
        #pragma unroll
        for (int dt = 0; dt < 2; ++dt)
        #pragma unroll
        for (int qt = 0; qt < 2; ++qt)
        #pragma unroll
        for (int r = 0; r < 16; ++r) {
            const int d = dt * 32 + (r & 3) + 8 * (r >> 2) + 4 * hi;
            sOb[d * 64 + qt * 32 + c31] = o_acc[dt][qt][r];
        }
    }
    __syncthreads();
    if (wv == 0) {
        #pragma unroll
        for (int dt = 0; dt < 2; ++dt)
        #pragma unroll
        for (int qt = 0; qt < 2; ++qt)
        #pragma unroll
        for (int r = 0; r < 16; ++r) {
            const int d = dt * 32 + (r & 3) + 8 * (r >> 2) + 4 * hi;
            o_acc[dt][qt][r] += sOb[d * 64 + qt * 32 + c31];
        }
        const int b  = bh >> 3;
        const int hh = bh & 7;
        #pragma unroll
        for (int qt = 0; qt < 2; ++qt) {
            const float lsum = sL[(0 * 2 + qt) * 32 + c31] + sL[(1 * 2 + qt) * 32 + c31]
                             + sL[(2 * 2 + qt) * 32 + c31] + sL[(3 * 2 + qt) * 32 + c31];
            const float rinv = 1.f / lsum;
            const int s = q0 + qt * 32 + c31;
            float* orow = out + ((size_t)b * S_LEN + s) * 512 + hh * 64;
            #pragma unroll
            for (int dt = 0; dt < 2; ++dt) {
                #pragma unroll
                for (int g = 0; g < 4; ++g) {
                    float4 vv;
                    vv.x = o_acc[dt][qt][4 * g + 0] * rinv;
                    vv.y = o_acc[dt][qt][4 * g + 1] * rinv;
                    vv.z = o_acc[dt][qt][4 * g + 2] * rinv;
                    vv.w = o_acc[dt][qt][4 * g + 3] * rinv;
                    *(float4*)(orow + dt * 32 + 8 * g + 4 * hi) = vv;
                }
            }
        }
    }
}

extern "C" void kernel_launch(void* const* d_in, const int* in_sizes, int n_in,
                              void* d_out, int out_size, void* d_ws, size_t ws_size,
                              hipStream_t stream) {
    (void)in_sizes; (void)n_in; (void)out_size;
    const float* q_in = (const float*)d_in[0];
    const float* k_in = (const float*)d_in[1];
    const float* v_in = (const float*)d_in[2];
    const float* Wq   = (const float*)d_in[3];
    const float* bq   = (const float*)d_in[4];
    const float* Wk   = (const float*)d_in[5];
    const float* bk   = (const float*)d_in[6];
    const float* Wv   = (const float*)d_in[7];
    const float* bv   = (const float*)d_in[8];
    unsigned short* ws = (unsigned short*)d_ws;
    float* out = (float*)d_out;

    if (ws_size >= WS_NEED_BYTES) {
        conv_frag3<<<dim3(272, 1, 3), 256, 0, stream>>>(
            q_in, k_in, v_in, Wq, Wk, Wv, ws + XFRAG_OFF, ws + WFRAG_OFF);
        qkv_gemm_rope<<<dim3(64, 4, 3), 256, 0, stream>>>(
            ws + XFRAG_OFF, ws + WFRAG_OFF, bq, bk, bv, ws + QKV_OFF);
        flash_attn_st<<<dim3(1024), 256, 0, stream>>>(ws + QKV_OFF, out);
    } else {
        qkv_rope_f32<<<dim3(64, 4, 3), 256, 0, stream>>>(
            q_in, k_in, v_in, Wq, bq, Wk, bk, Wv, bv, ws);
        flash_attn_st<<<dim3(1024), 256, 0, stream>>>(ws, out);
    }
}

// Round 8
// 207.610 us; speedup vs baseline: 1.0376x; 1.0376x over previous
//
#include <hip/hip_runtime.h>
#include <hip/hip_bf16.h>

#define S_LEN 4096
#define HDIM  64
#define NH    8

// ws layout (ushort element offsets), big-ws path:
//   XFRAG: 3 * 4194304   bf16 X (q,k,v inputs) in frag-tile layout
//   WFRAG: 3 * 262144    bf16 W in frag-tile layout
//   QKV:   Q(4194304) K(4194304) Vt(4194304), per-bh 262144, frag-tile layouts
#define XFRAG_OFF 0
#define WFRAG_OFF 12582912
#define QKV_OFF   13369344
#define WS_NEED_BYTES ((size_t)(13369344 + 12582912) * 2)      // 51,904,512

typedef short s16x8 __attribute__((ext_vector_type(8)));
typedef float f32x16 __attribute__((ext_vector_type(16)));
typedef unsigned short u16x4 __attribute__((ext_vector_type(4)));
typedef int i32x2 __attribute__((ext_vector_type(2)));

union FragU {
    s16x8 v;
    unsigned int u[4];
    unsigned short h[8];
};

static __device__ __forceinline__ unsigned int pack2_bf16(float a, float b) {
    __hip_bfloat162 h2 = __float22bfloat162_rn(float2{a, b});
    union { __hip_bfloat162 h; unsigned int u; } cv;
    cv.h = h2;
    return cv.u;
}

static __device__ __forceinline__ unsigned short to_bf16(float a) {
    __hip_bfloat16 h = __float2bfloat16(a);
    union { __hip_bfloat16 h; unsigned short u; } cv;
    cv.h = h;
    return cv.u;
}

// log2(e)/64 : folds the 1/hd score scale and exp->exp2 into Q
#define Q_PRESCALE 0.022542110f
// log2(1e8)/128
#define FREQ_L2 0.20762050593046f

// ---------------------------------------------------------------------------
// fp32 -> bf16 convert + reorder into MFMA frag-tile layout, LDS-staged
// (dense global reads AND dense global writes). Unchanged.
// grid (272,1,3), block 256.
// ---------------------------------------------------------------------------
__global__ __launch_bounds__(256) void conv_frag3(
    const float* __restrict__ qx, const float* __restrict__ kx,
    const float* __restrict__ vx,
    const float* __restrict__ Wq, const float* __restrict__ Wk,
    const float* __restrict__ Wv,
    unsigned short* __restrict__ xdst, unsigned short* __restrict__ wdst)
{
    __shared__ __align__(16) unsigned short slds[16640];   // 32*520 + pad

    const int z  = blockIdx.z;
    const int bx = blockIdx.x;
    const int tid  = threadIdx.x;
    const int w    = tid >> 6;
    const int lane = tid & 63;

    const float* src;
    unsigned short* dst;
    if (bx < 256) {
        src = ((z == 0) ? qx : ((z == 1) ? kx : vx)) + (size_t)bx * 32 * 512;
        dst = xdst + (size_t)z * 4194304 + (size_t)bx * 16384;
    } else {
        const int s = bx - 256;
        src = ((z == 0) ? Wq : ((z == 1) ? Wk : Wv)) + (size_t)s * 32 * 512;
        dst = wdst + (size_t)z * 262144 + (size_t)s * 16384;
    }

    #pragma unroll
    for (int i = 0; i < 8; ++i) {
        const int r = w * 8 + i;
        const float4* p = (const float4*)(src + (size_t)r * 512 + lane * 8);
        float4 x0 = p[0], x1 = p[1];
        FragU f;
        f.u[0] = pack2_bf16(x0.x, x0.y);
        f.u[1] = pack2_bf16(x0.z, x0.w);
        f.u[2] = pack2_bf16(x1.x, x1.y);
        f.u[3] = pack2_bf16(x1.z, x1.w);
        *(s16x8*)(slds + (lane >> 1) * 520 + ((lane & 1) * 32 + r) * 8) = f.v;
    }
    __syncthreads();

    #pragma unroll
    for (int i = 0; i < 8; ++i) {
        const int kc = w * 8 + i;
        s16x8 v = *(const s16x8*)(slds + kc * 520 + lane * 8);
        *(s16x8*)(dst + kc * 512 + lane * 8) = v;
    }
}

// ---------------------------------------------------------------------------
// Shared epilogue for the QKV GEMM (unchanged, verified r4-r7).
// ---------------------------------------------------------------------------
static __device__ __forceinline__ void qkv_epilogue(
    int z, const f32x16 acc[2][2], int m0, int n0, int c31, int hi,
    const float* __restrict__ bias, unsigned short* __restrict__ dst_base)
{
    if (z < 2) {
        unsigned short* dst = dst_base + (size_t)z * 4194304;
        #pragma unroll
        for (int nt = 0; nt < 2; ++nt) {
            const int s_g = n0 + nt * 32 + c31;       // global token
            const int b   = s_g >> 12;
            const int s   = s_g & 4095;
            const float pos0 = (float)(s >> 6);
            const float pos1 = (float)(s & 63);
            #pragma unroll
            for (int mt = 0; mt < 2; ++mt) {
                #pragma unroll
                for (int g = 0; g < 4; ++g) {
                    const int o_b = m0 + mt * 32 + 8 * g + 4 * hi;   // 4-aligned channel quad
                    const float4 bb = *(const float4*)(bias + o_b);
                    float v0 = acc[mt][nt][4 * g + 0] + bb.x;
                    float v1 = acc[mt][nt][4 * g + 1] + bb.y;
                    float v2 = acc[mt][nt][4 * g + 2] + bb.z;
                    float v3 = acc[mt][nt][4 * g + 3] + bb.w;
                    const float fr0 = exp2f(-(float)(o_b >> 2) * FREQ_L2);
                    float sn0, cs0, sn1, cs1;
                    __sincosf(pos0 * fr0, &sn0, &cs0);
                    __sincosf(pos1 * fr0, &sn1, &cs1);
                    float r0 = v0 * cs0 - v1 * sn0;
                    float r1 = v0 * sn0 + v1 * cs0;
                    float r2 = v2 * cs1 - v3 * sn1;
                    float r3 = v2 * sn1 + v3 * cs1;
                    if (z == 0) { r0 *= Q_PRESCALE; r1 *= Q_PRESCALE; r2 *= Q_PRESCALE; r3 *= Q_PRESCALE; }
                    const int bh = b * NH + (o_b >> 6);
                    const int k6 = o_b & 63;
                    u16x4 pk;
                    pk.x = to_bf16(r0); pk.y = to_bf16(r1);
                    pk.z = to_bf16(r2); pk.w = to_bf16(r3);
                    const size_t off = (size_t)bh * 262144 + (s >> 5) * 2048
                                     + (k6 >> 4) * 512 + (((k6 >> 3) & 1) * 32 + (s & 31)) * 8 + (k6 & 7);
                    *(u16x4*)(dst + off) = pk;
                }
            }
        }
    } else {
        unsigned short* dst = dst_base + 8388608;
        #pragma unroll
        for (int nt = 0; nt < 2; ++nt) {
            const int o  = n0 + nt * 32 + c31;        // channel (per lane)
            const float bv_ = bias[o];
            const int d = o & 63, hh = o >> 6;
            #pragma unroll
            for (int mt = 0; mt < 2; ++mt) {
                #pragma unroll
                for (int g = 0; g < 4; ++g) {
                    const int s_b = m0 + mt * 32 + 8 * g + 4 * hi;  // 4-aligned token quad
                    const int b = s_b >> 12;
                    const int s = s_b & 4095;
                    const int bh = b * NH + hh;
                    u16x4 pk;
                    pk.x = to_bf16(acc[mt][nt][4 * g + 0] + bv_);
                    pk.y = to_bf16(acc[mt][nt][4 * g + 1] + bv_);
                    pk.z = to_bf16(acc[mt][nt][4 * g + 2] + bv_);
                    pk.w = to_bf16(acc[mt][nt][4 * g + 3] + bv_);
                    const size_t off = (size_t)bh * 262144 + (s >> 5) * 2048 + (d >> 5) * 1024
                                     + ((s >> 4) & 1) * 512 + (((s >> 3) & 1) * 32 + (d & 31)) * 8 + (s & 7);
                    *(u16x4*)(dst + off) = pk;
                }
            }
        }
    }
}

// ---------------------------------------------------------------------------
// Kernel 1: QKV projection GEMM from frag-tile bf16 operands.
//   r7 (unmeasured — infra failure; resubmitted unchanged): async global->LDS
//   staging via global_load_lds (width 16), double-buffered, 2 kc per step
//   (16KB/step, 32KB LDS). The compiler never auto-emits this
//   (Common-mistake #1); r6's register-dbuf was a null because the unrolled
//   loop was already load-hoisted — the missing piece is ASYNC staging whose
//   latency hides under the previous step's MFMAs. Frag-tile chunks are
//   lane*16B-linear, exactly matching global_load_lds's uniform-base +
//   lane*16 write pattern (no swizzle needed).
//   Per step: 4 waves x 4 global_load_lds stage the next 16 chunks; each
//   wave ds_read_b128 its 4 frags x2 kc and issues 8 MFMAs; one barrier
//   (compiler's vmcnt drain there guarantees staged data before next reads).
// grid (64, 4, 3), block 256.
// ---------------------------------------------------------------------------
__global__ __launch_bounds__(256) void qkv_gemm_rope(
    const unsigned short* __restrict__ xf, const unsigned short* __restrict__ wf,
    const float* __restrict__ bq, const float* __restrict__ bk,
    const float* __restrict__ bv, unsigned short* __restrict__ dst_base)
{
    __shared__ __align__(16) unsigned char gsm[2][16384];  // 2 buf x 16 chunks x 1KB

    const int z = blockIdx.z;
    const float* bias = (z == 0) ? bq : ((z == 1) ? bk : bv);
    const unsigned short* X = xf + (size_t)z * 4194304;
    const unsigned short* W = wf + (size_t)z * 262144;

    const int tid  = threadIdx.x;
    const int wv   = tid >> 6;
    const int lane = tid & 63;
    const int c31  = lane & 31;
    const int hi   = lane >> 5;
    const int wm   = wv >> 1, wn = wv & 1;

    int m0, n0, ablk, bblk;
    const unsigned short *A, *B;
    if (z < 2) {  // transposed: A = W (channels), B = X (tokens)
        m0 = blockIdx.y * 128 + wm * 64;
        n0 = blockIdx.x * 128 + wn * 64;
        A = W; B = X; ablk = blockIdx.y; bblk = blockIdx.x;
    } else {      // normal: A = X (tokens), B = W (channels)
        m0 = blockIdx.x * 128 + wm * 64;
        n0 = blockIdx.y * 128 + wn * 64;
        A = X; B = W; ablk = blockIdx.x; bblk = blockIdx.y;
    }
    const unsigned short* Ab = A + (size_t)ablk * 4 * 16384;   // block's 4 A row-tiles
    const unsigned short* Bb = B + (size_t)bblk * 4 * 16384;   // block's 4 B row-tiles

    f32x16 acc[2][2];
    #pragma unroll
    for (int a = 0; a < 2; ++a)
    #pragma unroll
    for (int b = 0; b < 2; ++b)
    #pragma unroll
    for (int r = 0; r < 16; ++r) acc[a][b][r] = 0.f;

    // chunk c = wv*4+j : ko=c>>3 (kc within step), isB=(c>>2)&1, tile=c&3
#define QSTAGE(BUF, KC0)                                                      \
    do {                                                                      \
        _Pragma("unroll")                                                     \
        for (int j = 0; j < 4; ++j) {                                         \
            const int c_  = wv * 4 + j;                                       \
            const int ko_ = c_ >> 3;                                          \
            const int tl_ = c_ & 3;                                           \
            const unsigned short* g_ = (((c_ >> 2) & 1) ? Bb : Ab)            \
                + (size_t)tl_ * 16384 + (size_t)((KC0) + ko_) * 512 + lane * 8; \
            __builtin_amdgcn_global_load_lds(                                 \
                (const __attribute__((address_space(1))) void*)g_,            \
                (__attribute__((address_space(3))) void*)(&gsm[BUF][c_ * 1024]), \
                16, 0, 0);                                                    \
        }                                                                     \
    } while (0)

    QSTAGE(0, 0);
    __syncthreads();               // vmcnt drain: buf0 staged

    const int a_t0 = wm * 2, b_t0 = wn * 2;
    for (int s = 0; s < 16; ++s) {
        const int cur = s & 1;
        if (s < 15) QSTAGE(cur ^ 1, (s + 1) * 2);   // async: hides under MFMAs
        #pragma unroll
        for (int ko = 0; ko < 2; ++ko) {
            const unsigned char* base = gsm[cur] + ko * 8192;
            s16x8 a0 = *(const s16x8*)(base + (size_t)(a_t0 + 0) * 1024 + lane * 16);
            s16x8 a1 = *(const s16x8*)(base + (size_t)(a_t0 + 1) * 1024 + lane * 16);
            s16x8 b0 = *(const s16x8*)(base + 4096 + (size_t)(b_t0 + 0) * 1024 + lane * 16);
            s16x8 b1 = *(const s16x8*)(base + 4096 + (size_t)(b_t0 + 1) * 1024 + lane * 16);
            acc[0][0] = __builtin_amdgcn_mfma_f32_32x32x16_bf16(a0, b0, acc[0][0], 0, 0, 0);
            acc[0][1] = __builtin_amdgcn_mfma_f32_32x32x16_bf16(a0, b1, acc[0][1], 0, 0, 0);
            acc[1][0] = __builtin_amdgcn_mfma_f32_32x32x16_bf16(a1, b0, acc[1][0], 0, 0, 0);
            acc[1][1] = __builtin_amdgcn_mfma_f32_32x32x16_bf16(a1, b1, acc[1][1], 0, 0, 0);
        }
        __syncthreads();           // reads of buf[cur] done + stage(s+1) drained
    }
#undef QSTAGE

    qkv_epilogue(z, acc, m0, n0, c31, hi, bias, dst_base);
}

// ---------------------------------------------------------------------------
// Kernel 1 fallback (fp32 inputs directly; used only if ws too small).
// ---------------------------------------------------------------------------
__global__ __launch_bounds__(256) void qkv_rope_f32(
    const float* __restrict__ q_in, const float* __restrict__ k_in,
    const float* __restrict__ v_in,
    const float* __restrict__ Wq, const float* __restrict__ bq,
    const float* __restrict__ Wk, const float* __restrict__ bk,
    const float* __restrict__ Wv, const float* __restrict__ bv,
    unsigned short* __restrict__ dst_base)
{
    const int z = blockIdx.z;
    const float* Xr = (z == 0) ? q_in : ((z == 1) ? k_in : v_in);
    const float* Wr = (z == 0) ? Wq   : ((z == 1) ? Wk   : Wv);
    const float* bias = (z == 0) ? bq : ((z == 1) ? bk : bv);

    const int tid  = threadIdx.x;
    const int wv   = tid >> 6;
    const int lane = tid & 63;
    const int c31  = lane & 31;
    const int hi   = lane >> 5;
    const int wm   = wv >> 1, wn = wv & 1;

    int m0, n0;
    const float *A, *B;
    if (z < 2) { m0 = blockIdx.y * 128 + wm * 64; n0 = blockIdx.x * 128 + wn * 64; A = Wr; B = Xr; }
    else       { m0 = blockIdx.x * 128 + wm * 64; n0 = blockIdx.y * 128 + wn * 64; A = Xr; B = Wr; }

    f32x16 acc[2][2];
    #pragma unroll
    for (int a = 0; a < 2; ++a)
    #pragma unroll
    for (int b = 0; b < 2; ++b)
    #pragma unroll
    for (int r = 0; r < 16; ++r) acc[a][b][r] = 0.f;

    for (int kc = 0; kc < 32; ++kc) {
        const int kofs = kc * 16 + hi * 8;
        FragU a_f[2], b_f[2];
        #pragma unroll
        for (int mt = 0; mt < 2; ++mt) {
            const float4* p = (const float4*)(A + (size_t)(m0 + mt * 32 + c31) * 512 + kofs);
            float4 x0 = p[0], x1 = p[1];
            a_f[mt].u[0] = pack2_bf16(x0.x, x0.y);
            a_f[mt].u[1] = pack2_bf16(x0.z, x0.w);
            a_f[mt].u[2] = pack2_bf16(x1.x, x1.y);
            a_f[mt].u[3] = pack2_bf16(x1.z, x1.w);
        }
        #pragma unroll
        for (int nt = 0; nt < 2; ++nt) {
            const float4* p = (const float4*)(B + (size_t)(n0 + nt * 32 + c31) * 512 + kofs);
            float4 x0 = p[0], x1 = p[1];
            b_f[nt].u[0] = pack2_bf16(x0.x, x0.y);
            b_f[nt].u[1] = pack2_bf16(x0.z, x0.w);
            b_f[nt].u[2] = pack2_bf16(x1.x, x1.y);
            b_f[nt].u[3] = pack2_bf16(x1.z, x1.w);
        }
        #pragma unroll
        for (int mt = 0; mt < 2; ++mt)
        #pragma unroll
        for (int nt = 0; nt < 2; ++nt)
            acc[mt][nt] = __builtin_amdgcn_mfma_f32_32x32x16_bf16(
                a_f[mt].v, b_f[nt].v, acc[mt][nt], 0, 0, 0);
    }

    qkv_epilogue(z, acc, m0, n0, c31, hi, bias, dst_base);
}

// ---------------------------------------------------------------------------
// P-fragment build from 4 packed-bf16 words via v_permlane32_swap_b32.
// (r3-verified, flash 180->159us). One instr yields two fragment words.
// ---------------------------------------------------------------------------
static __device__ __forceinline__ s16x8 build_pfrag(
    unsigned int a0, unsigned int a1, unsigned int a2, unsigned int a3)
{
    i32x2 r02 = __builtin_amdgcn_permlane32_swap((int)a0, (int)a2, false, false);
    i32x2 r13 = __builtin_amdgcn_permlane32_swap((int)a1, (int)a3, false, false);
    FragU pb;
    pb.u[0] = (unsigned int)r02.x;
    pb.u[1] = (unsigned int)r13.x;
    pb.u[2] = (unsigned int)r02.y;
    pb.u[3] = (unsigned int)r13.y;
    return pb.v;
}

// ---------------------------------------------------------------------------
// Kernel 2: flash attention (S^T trick) — exact r5 body (85.4us verified:
// Q reg-hoisted, launch_bounds(256,2), permlane pfrag, V single-buffer,
// in-loop st zeroing). r6's zero-C trick REVERTED: it pinned 16 registers
// and slowed the chain heads (85.4 -> 88.2, MfmaUtil 35 -> 33.5).
// grid (1024), block 256.
// ---------------------------------------------------------------------------
__global__ __launch_bounds__(256, 2) void flash_attn_st(
    const unsigned short* __restrict__ qkv, float* __restrict__ out)
{
    __shared__ __align__(16) unsigned char smem[32768 + 1024];
    unsigned short* sQ = (unsigned short*)smem;            // 8KB, prologue only
    float* sOb = (float*)smem;                             // 32KB, epilogue only
    float* sL  = (float*)(smem + 32768);                   // 1KB, disjoint from sQ

    const int tid  = threadIdx.x;
    const int wv   = tid >> 6;       // kv-split index 0..3
    const int lane = tid & 63;
    const int c31  = lane & 31;
    const int hi   = lane >> 5;
    const int id   = blockIdx.x;
    const int bh   = id & 15;        // id % 8 == bh % 8  -> XCD-local K/V
    const int q0   = (id >> 4) * 64;

    const unsigned short* Qb  = qkv + (size_t)bh * 262144;
    const unsigned short* Kb  = qkv + (size_t)4194304 + (size_t)bh * 262144;
    const unsigned short* Vtb = qkv + (size_t)8388608 + (size_t)bh * 262144;

    // cooperative Q -> LDS (8 chunks x 64 entries x 16B)
    #pragma unroll
    for (int i = 0; i < 2; ++i) {
        const int idx   = tid + i * 256;
        const int chunk = idx >> 6;
        const int ln    = idx & 63;
        *(s16x8*)(sQ + chunk * 512 + ln * 8) =
            *(const s16x8*)(Qb + (size_t)((q0 >> 5) + (chunk >> 2)) * 2048 + (chunk & 3) * 512 + ln * 8);
    }
    __syncthreads();

    // Q fragments: LDS -> registers ONCE (r5-verified win).
    s16x8 qf0[4], qf1[4];
    #pragma unroll
    for (int kc = 0; kc < 4; ++kc) {
        qf0[kc] = *(const s16x8*)(sQ + kc * 512 + lane * 8);
        qf1[kc] = *(const s16x8*)(sQ + 2048 + kc * 512 + lane * 8);
    }

    f32x16 o_acc[2][2];                   // [d-tile][q-tile], O^T layout
    #pragma unroll
    for (int a = 0; a < 2; ++a)
    #pragma unroll
    for (int b = 0; b < 2; ++b)
    #pragma unroll
    for (int r = 0; r < 16; ++r) o_acc[a][b][r] = 0.f;
    float l_acc[2] = {0.f, 0.f};

    const unsigned short* kp = Kb  + (size_t)wv * 2048 + lane * 8;   // += 8192/iter
    const unsigned short* vp = Vtb + (size_t)wv * 2048 + lane * 8;   // += 8192/iter

    // preload K A-frags for iter 0
    s16x8 ka[4];
    #pragma unroll
    for (int kc = 0; kc < 4; ++kc)
        ka[kc] = *(const s16x8*)(kp + kc * 512);

    for (int it = 0; it < 32; ++it) {
        // ---- issue V^T A-frag loads now; consumed at PV ----
        s16x8 va[2][2];
        va[0][0] = *(const s16x8*)(vp);
        va[0][1] = *(const s16x8*)(vp + 512);
        va[1][0] = *(const s16x8*)(vp + 1024);
        va[1][1] = *(const s16x8*)(vp + 1536);
        vp += 8192;

        // ---- S^T(q0) then S^T(q1): both chains queued on the matrix pipe ----
        f32x16 st0, st1;
        #pragma unroll
        for (int r = 0; r < 16; ++r) { st0[r] = 0.f; st1[r] = 0.f; }
        __builtin_amdgcn_s_setprio(1);
        #pragma unroll
        for (int kc = 0; kc < 4; ++kc)
            st0 = __builtin_amdgcn_mfma_f32_32x32x16_bf16(ka[kc], qf0[kc], st0, 0, 0, 0);
        #pragma unroll
        for (int kc = 0; kc < 4; ++kc)
            st1 = __builtin_amdgcn_mfma_f32_32x32x16_bf16(ka[kc], qf1[kc], st1, 0, 0, 0);
        __builtin_amdgcn_s_setprio(0);

        // ---- prefetch next iter's K into the SAME ka regs (after last use) ----
        kp += 8192;
        if (it < 31) {
            #pragma unroll
            for (int kc = 0; kc < 4; ++kc)
                ka[kc] = *(const s16x8*)(kp + kc * 512);
        }

        // ---- q0: exp + pack + l (VALU, overlaps q1's queued S^T MFMAs) ----
        unsigned int up0[8];
        {
            float ls0 = 0.f, ls1 = 0.f;
            #pragma unroll
            for (int qq = 0; qq < 8; ++qq) {
                float p0 = __builtin_amdgcn_exp2f(st0[2 * qq]);
                float p1 = __builtin_amdgcn_exp2f(st0[2 * qq + 1]);
                ls0 += p0; ls1 += p1;
                up0[qq] = pack2_bf16(p0, p1);
            }
            l_acc[0] += ls0 + ls1;
        }

        // ---- PV(q0): queued on matrix pipe before q1's exp runs on VALU ----
        #pragma unroll
        for (int k2 = 0; k2 < 2; ++k2) {
            s16x8 pfrag = build_pfrag(up0[4 * k2 + 0], up0[4 * k2 + 1],
                                      up0[4 * k2 + 2], up0[4 * k2 + 3]);
            __builtin_amdgcn_s_setprio(1);
            #pragma unroll
            for (int dt = 0; dt < 2; ++dt)
                o_acc[dt][0] = __builtin_amdgcn_mfma_f32_32x32x16_bf16(
                    va[dt][k2], pfrag, o_acc[dt][0], 0, 0, 0);
            __builtin_amdgcn_s_setprio(0);
        }

        // ---- q1: exp + pack + l (VALU, overlaps PV(q0) MFMAs) ----
        unsigned int up1[8];
        {
            float ls0 = 0.f, ls1 = 0.f;
            #pragma unroll
            for (int qq = 0; qq < 8; ++qq) {
                float p0 = __builtin_amdgcn_exp2f(st1[2 * qq]);
                float p1 = __builtin_amdgcn_exp2f(st1[2 * qq + 1]);
                ls0 += p0; ls1 += p1;
                up1[qq] = pack2_bf16(p0, p1);
            }
            l_acc[1] += ls0 + ls1;
        }

        // ---- PV(q1) ----
        #pragma unroll
        for (int k2 = 0; k2 < 2; ++k2) {
            s16x8 pfrag = build_pfrag(up1[4 * k2 + 0], up1[4 * k2 + 1],
                                      up1[4 * k2 + 2], up1[4 * k2 + 3]);
            __builtin_amdgcn_s_setprio(1);
            #pragma unroll
            for (int dt = 0; dt < 2; ++dt)
                o_acc[dt][1] = __builtin_amdgcn_mfma_f32_32x32x16_bf16(
                    va[dt][k2], pfrag, o_acc[dt][1], 0, 0, 0);
            __builtin_amdgcn_s_setprio(0);
        }
    }

    // ---- merge partials across the 4 kv-split waves (r4-verified) ----
    // sL is disjoint from sQ; sQ itself is dead after the prologue reads.
    {
        float l0 = l_acc[0] + __shfl_xor(l_acc[0], 32);
        float l1 = l_acc[1] + __shfl_xor(l_acc[1], 32);
        if (lane < 32) {
            sL[(wv * 2 + 0) * 32 + lane] = l0;
            sL[(wv * 2 + 1) * 32 + lane] = l1;
        }
    }
    __syncthreads();
    // All waves past the loop: the sOb region (aliasing sQ) is free to use.

    if (wv == 1 || wv == 2) {
        float* buf = sOb + (wv - 1) * 4096;
        #pragma unroll
        for (int dt = 0; dt < 2; ++dt)
        #pragma unroll
        for (int qt = 0; qt < 2; ++qt)
        #pragma unroll
        for (int r = 0; r < 16; ++r) {
            const int d = dt * 32 + (r & 3) + 8 * (r >> 2) + 4 * hi;
            buf[d * 64 + qt * 32 + c31] = o_acc[dt][qt][r];
        }
    }
    __syncthreads();
    if (wv == 0 || wv == 3) {
        const float* buf = sOb + ((wv == 0) ? 0 : 4096);
        #pragma unroll
        for (int dt = 0; dt < 2; ++dt)
        #pragma unroll
        for (int qt = 0; qt < 2; ++qt)
        #pragma unroll
        for (int r = 0; r < 16; ++r) {
            const int d = dt * 32 + (r & 3) + 8 * (r >> 2) + 4 * hi;
            o_acc[dt][qt][r] += buf[d * 64 + qt * 32 + c31];
        }
    }
    __syncthreads();
    if (wv == 3) {
        #pragma unroll
        for (int dt = 0; dt < 2; ++dt)
        #pragma unroll
        for (int qt = 0; qt < 2; ++qt)
        #pragma unroll
        for (int r = 0; r < 16; ++r) {
            const int d = dt * 32 + (r & 3) + 8 * (r >> 2) + 4 * hi;
            sOb[d * 64 + qt * 32 + c31] = o_acc[dt][qt][r];
        }
    }
    __syncthreads();
    if (wv == 0) {
        #pragma unroll
        for (int dt = 0; dt < 2; ++dt)
        #pragma unroll
        for (int qt = 0; qt < 2; ++qt)
        #pragma unroll
        for (int r = 0; r < 16; ++r) {
            const int d = dt * 32 + (r & 3) + 8 * (r >> 2) + 4 * hi;
            o_acc[dt][qt][r] += sOb[d * 64 + qt * 32 + c31];
        }
        const int b  = bh >> 3;
        const int hh = bh & 7;
        #pragma unroll
        for (int qt = 0; qt < 2; ++qt) {
            const float lsum = sL[(0 * 2 + qt) * 32 + c31] + sL[(1 * 2 + qt) * 32 + c31]
                             + sL[(2 * 2 + qt) * 32 + c31] + sL[(3 * 2 + qt) * 32 + c31];
            const float rinv = 1.f / lsum;
            const int s = q0 + qt * 32 + c31;
            float* orow = out + ((size_t)b * S_LEN + s) * 512 + hh * 64;
            #pragma unroll
            for (int dt = 0; dt < 2; ++dt) {
                #pragma unroll
                for (int g = 0; g < 4; ++g) {
                    float4 vv;
                    vv.x = o_acc[dt][qt][4 * g + 0] * rinv;
                    vv.y = o_acc[dt][qt][4 * g + 1] * rinv;
                    vv.z = o_acc[dt][qt][4 * g + 2] * rinv;
                    vv.w = o_acc[dt][qt][4 * g + 3] * rinv;
                    *(float4*)(orow + dt * 32 + 8 * g + 4 * hi) = vv;
                }
            }
        }
    }
}

extern "C" void kernel_launch(void* const* d_in, const int* in_sizes, int n_in,
                              void* d_out, int out_size, void* d_ws, size_t ws_size,
                              hipStream_t stream) {
    (void)in_sizes; (void)n_in; (void)out_size;
    const float* q_in = (const float*)d_in[0];
    const float* k_in = (const float*)d_in[1];
    const float* v_in = (const float*)d_in[2];
    const float* Wq   = (const float*)d_in[3];
    const float* bq   = (const float*)d_in[4];
    const float* Wk   = (const float*)d_in[5];
    const float* bk   = (const float*)d_in[6];
    const float* Wv   = (const float*)d_in[7];
    const float* bv   = (const float*)d_in[8];
    unsigned short* ws = (unsigned short*)d_ws;
    float* out = (float*)d_out;

    if (ws_size >= WS_NEED_BYTES) {
        conv_frag3<<<dim3(272, 1, 3), 256, 0, stream>>>(
            q_in, k_in, v_in, Wq, Wk, Wv, ws + XFRAG_OFF, ws + WFRAG_OFF);
        qkv_gemm_rope<<<dim3(64, 4, 3), 256, 0, stream>>>(
            ws + XFRAG_OFF, ws + WFRAG_OFF, bq, bk, bv, ws + QKV_OFF);
        flash_attn_st<<<dim3(1024), 256, 0, stream>>>(ws + QKV_OFF, out);
    } else {
        qkv_rope_f32<<<dim3(64, 4, 3), 256, 0, stream>>>(
            q_in, k_in, v_in, Wq, bq, Wk, bk, Wv, bv, ws);
        flash_attn_st<<<dim3(1024), 256, 0, stream>>>(ws, out);
    }
}